// Round 2
// baseline (58.386 us; speedup 1.0000x reference)
//
#include <hip/hip_runtime.h>

#define NDENSE 13
#define NSPARSE 26
#define ROW_F4 156   // 39*16/4 float4 per v row
#define BATCH 4096
#define GEMM_ROWS 64 // rows per block in dense_gemm

// ---------------------------------------------------------------------------
// Kernel A: DV[b][e] = sum_d dense[b][d] * v[d][e]   (rank-13 GEMM, [4096,624])
// v[:13] (32.4 KB) staged in LDS once per block; 64 rows per block.
__global__ __launch_bounds__(256) void dense_gemm(
    const float*  __restrict__ dense,   // [B,13]
    const float4* __restrict__ v4,      // [26013*156]
    float4*       __restrict__ dv_out)  // [B*156]
{
    __shared__ float4 vsh[NDENSE * ROW_F4];   // 32448 B
    __shared__ float  dsh[GEMM_ROWS * NDENSE];

    const int t = threadIdx.x;
    for (int i = t; i < NDENSE * ROW_F4; i += 256) vsh[i] = v4[i];
    const int row0 = blockIdx.x * GEMM_ROWS;
    for (int i = t; i < GEMM_ROWS * NDENSE; i += 256)
        dsh[i] = dense[row0 * NDENSE + i];
    __syncthreads();

    const int r  = t >> 2;   // 0..63 local row
    const int c0 = t & 3;    // f4-column phase
    float dl[NDENSE];
#pragma unroll
    for (int d = 0; d < NDENSE; ++d) dl[d] = dsh[r * NDENSE + d];

#pragma unroll 4
    for (int i = 0; i < ROW_F4 / 4; ++i) {       // 39 columns per thread
        const int e = c0 + 4 * i;
        float4 acc = make_float4(0.f, 0.f, 0.f, 0.f);
#pragma unroll
        for (int d = 0; d < NDENSE; ++d) {
            const float4 vv = vsh[d * ROW_F4 + e];
            acc.x += dl[d] * vv.x; acc.y += dl[d] * vv.y;
            acc.z += dl[d] * vv.z; acc.w += dl[d] * vv.w;
        }
        dv_out[(size_t)(row0 + r) * ROW_F4 + e] = acc;
    }
}

// ---------------------------------------------------------------------------
// Kernel B: gathers + FM reduction, dense part read precomputed from DV.
__global__ __launch_bounds__(256) void ffm_gather(
    const float*  __restrict__ dense,
    const int*    __restrict__ sparse,
    const float*  __restrict__ w0,
    const float*  __restrict__ w,
    const float4* __restrict__ v4,
    const float4* __restrict__ dvp,     // [B*156] precomputed dense field
    float*        __restrict__ out)
{
    const int wave = threadIdx.x >> 6;
    const int lane = threadIdx.x & 63;
    const int b = blockIdx.x * 4 + wave;

    int myidx = 0;
    if (lane < NSPARSE) myidx = sparse[b * NSPARSE + lane] + NDENSE + 1000 * lane;

    float4 s = make_float4(0.f, 0.f, 0.f, 0.f);
    float  sq = 0.f;

#pragma unroll
    for (int p = 0; p < 3; ++p) {
        const int e4 = lane + 64 * p;
        if (e4 < ROW_F4) {
            float4 acc = dvp[(size_t)b * ROW_F4 + e4];   // dense field, 1 load
#pragma unroll
            for (int j = 0; j < NSPARSE; ++j) {
                const int ij = __shfl(myidx, j);
                const float4 vv = v4[(size_t)ij * ROW_F4 + e4];
                acc.x += vv.x; acc.y += vv.y; acc.z += vv.z; acc.w += vv.w;
            }
            // e4 & 3 == lane & 3 for all passes -> fixed k-group per lane
            s.x += acc.x; s.y += acc.y; s.z += acc.z; s.w += acc.w;
            sq  += acc.x * acc.x + acc.y * acc.y + acc.z * acc.z + acc.w * acc.w;
        }
    }

#pragma unroll
    for (int m = 4; m <= 32; m <<= 1) {
        s.x += __shfl_xor(s.x, m);
        s.y += __shfl_xor(s.y, m);
        s.z += __shfl_xor(s.z, m);
        s.w += __shfl_xor(s.w, m);
    }
    float s2 = s.x * s.x + s.y * s.y + s.z * s.z + s.w * s.w;
    s2 += __shfl_xor(s2, 1);
    s2 += __shfl_xor(s2, 2);

#pragma unroll
    for (int m = 1; m <= 32; m <<= 1) sq += __shfl_xor(sq, m);

    float fo = 0.f;
    if (lane < NSPARSE) fo = w[myidx];
    if (lane < NDENSE)  fo += dense[b * NDENSE + lane] * w[lane];
#pragma unroll
    for (int m = 1; m <= 32; m <<= 1) fo += __shfl_xor(fo, m);

    if (lane == 0) out[b] = w0[0] + fo + 0.5f * (s2 - sq);
}

// ---------------------------------------------------------------------------
// Fallback: R1 fused kernel (used only if ws_size is too small for DV).
__global__ __launch_bounds__(256) void ffm_fused(
    const float* __restrict__ dense, const int* __restrict__ sparse,
    const float* __restrict__ w0, const float* __restrict__ w,
    const float4* __restrict__ v4, float* __restrict__ out)
{
    const int wave = threadIdx.x >> 6;
    const int lane = threadIdx.x & 63;
    const int b = blockIdx.x * 4 + wave;

    float dv[NDENSE];
#pragma unroll
    for (int d = 0; d < NDENSE; ++d) dv[d] = dense[b * NDENSE + d];

    int myidx = 0;
    if (lane < NSPARSE) myidx = sparse[b * NSPARSE + lane] + NDENSE + 1000 * lane;

    float4 s = make_float4(0.f, 0.f, 0.f, 0.f);
    float  sq = 0.f;
#pragma unroll
    for (int p = 0; p < 3; ++p) {
        const int e4 = lane + 64 * p;
        if (e4 < ROW_F4) {
            float4 acc = make_float4(0.f, 0.f, 0.f, 0.f);
#pragma unroll
            for (int d = 0; d < NDENSE; ++d) {
                const float4 vv = v4[d * ROW_F4 + e4];
                acc.x += dv[d] * vv.x; acc.y += dv[d] * vv.y;
                acc.z += dv[d] * vv.z; acc.w += dv[d] * vv.w;
            }
#pragma unroll
            for (int j = 0; j < NSPARSE; ++j) {
                const int ij = __shfl(myidx, j);
                const float4 vv = v4[(size_t)ij * ROW_F4 + e4];
                acc.x += vv.x; acc.y += vv.y; acc.z += vv.z; acc.w += vv.w;
            }
            s.x += acc.x; s.y += acc.y; s.z += acc.z; s.w += acc.w;
            sq  += acc.x * acc.x + acc.y * acc.y + acc.z * acc.z + acc.w * acc.w;
        }
    }
#pragma unroll
    for (int m = 4; m <= 32; m <<= 1) {
        s.x += __shfl_xor(s.x, m); s.y += __shfl_xor(s.y, m);
        s.z += __shfl_xor(s.z, m); s.w += __shfl_xor(s.w, m);
    }
    float s2 = s.x * s.x + s.y * s.y + s.z * s.z + s.w * s.w;
    s2 += __shfl_xor(s2, 1);
    s2 += __shfl_xor(s2, 2);
#pragma unroll
    for (int m = 1; m <= 32; m <<= 1) sq += __shfl_xor(sq, m);
    float fo = 0.f;
    if (lane < NSPARSE) fo = w[myidx];
    if (lane < NDENSE)  fo += dense[b * NDENSE + lane] * w[lane];
#pragma unroll
    for (int m = 1; m <= 32; m <<= 1) fo += __shfl_xor(fo, m);
    if (lane == 0) out[b] = w0[0] + fo + 0.5f * (s2 - sq);
}

extern "C" void kernel_launch(void* const* d_in, const int* in_sizes, int n_in,
                              void* d_out, int out_size, void* d_ws, size_t ws_size,
                              hipStream_t stream) {
    const float*  dense  = (const float*)d_in[0];
    const int*    sparse = (const int*)d_in[1];
    const float*  w0     = (const float*)d_in[2];
    const float*  w      = (const float*)d_in[3];
    const float4* v4     = (const float4*)d_in[4];
    float* out = (float*)d_out;

    const size_t dv_bytes = (size_t)BATCH * ROW_F4 * sizeof(float4); // 10.2 MB

    if (ws_size >= dv_bytes) {
        float4* dvp = (float4*)d_ws;
        hipLaunchKernelGGL(dense_gemm, dim3(BATCH / GEMM_ROWS), dim3(256), 0, stream,
                           dense, v4, dvp);
        hipLaunchKernelGGL(ffm_gather, dim3(BATCH / 4), dim3(256), 0, stream,
                           dense, sparse, w0, w, v4, dvp, out);
    } else {
        hipLaunchKernelGGL(ffm_fused, dim3(BATCH / 4), dim3(256), 0, stream,
                           dense, sparse, w0, w, v4, out);
    }
}

// Round 3
// 48.680 us; speedup vs baseline: 1.1994x; 1.1994x over previous
//
#include <hip/hip_runtime.h>

#define NDENSE 13
#define NSPARSE 26
#define NSRC 39      // 26 sparse gathers + 13 dense-weighted rows
#define ROW_F4 156   // 39*16/4 float4 per v row
#define BATCH 4096
#define CHUNKS 256   // row-chunks per slice
#define RPB 16       // rows per block
#define RPW 4        // rows per wave

// ---------------------------------------------------------------------------
// Phase 1: XCD-pinned sliced gather. blockIdx%8 ~ XCD (round-robin dispatch).
// XCD x owns column-slices {2x, 2x+1}, processed temporally (seq<256 then >=256)
// so its 4MB L2 holds one slice's working set (26013 rows x 160B = 4.16MB).
// Writes COMPLETE field_f values (dense + all 26 gathers) for its columns.
__global__ __launch_bounds__(256) void ffm_slice(
    const float*  __restrict__ dense,    // [B,13]
    const int*    __restrict__ sparse,   // [B,26]
    const float4* __restrict__ v4,       // [26013*156]
    float4*       __restrict__ ff)       // [B*156] field_f output
{
    const int xcd   = blockIdx.x & 7;
    const int seq   = blockIdx.x >> 3;                 // 0..511 per XCD
    const int slice = 2 * xcd + (seq >= CHUNKS ? 1 : 0);
    const int chunk = seq & (CHUNKS - 1);
    int sb, W;                                          // slice base/width in float4
    if (slice < 12) { sb = 10 * slice;            W = 10; }
    else            { sb = 120 + 9 * (slice - 12); W = 9; }

    // Unified per-row source table: (v-row, weight) for all 39 sources.
    __shared__ int   vrow_s[RPB][NSRC];
    __shared__ float wgt_s [RPB][NSRC];

    const int t = threadIdx.x;
    const int row0 = chunk * RPB;
    for (int i = t; i < RPB * NSPARSE; i += 256) {
        const int r = i / NSPARSE, j = i % NSPARSE;
        vrow_s[r][j] = sparse[(row0 + r) * NSPARSE + j] + NDENSE + 1000 * j;
        wgt_s [r][j] = 1.0f;
    }
    for (int i = t; i < RPB * NDENSE; i += 256) {
        const int r = i / NDENSE, d = i % NDENSE;
        vrow_s[r][NSPARSE + d] = d;
        wgt_s [r][NSPARSE + d] = dense[(row0 + r) * NDENSE + d];
    }
    __syncthreads();

    const int lane = t & 63;
    const int wv   = t >> 6;
    const int e    = lane % 10;        // column within slice
    const int jl   = lane / 10;        // source group (6 groups, lanes 60-63 idle)
    const bool act = (jl < 6) && (e < W);

    for (int rr = 0; rr < RPW; ++rr) {
        const int rloc = wv * RPW + rr;
        float4 acc = make_float4(0.f, 0.f, 0.f, 0.f);
#pragma unroll
        for (int st = 0; st < 7; ++st) {
            const int src = jl + 6 * st;              // 0..41, masked at 39
            if (act && src < NSRC) {
                const int   vr = vrow_s[rloc][src];
                const float wg = wgt_s [rloc][src];
                const float4 g = v4[(unsigned)vr * ROW_F4 + (unsigned)(sb + e)];
                acc.x += wg * g.x; acc.y += wg * g.y;
                acc.z += wg * g.z; acc.w += wg * g.w;
            }
        }
        // T[e] = sum over 6 jl-groups of acc[jl*10+e]; idle lanes hold 0.
        float4 q, T;
        q.x = acc.x + __shfl(acc.x, lane + 30);
        q.y = acc.y + __shfl(acc.y, lane + 30);
        q.z = acc.z + __shfl(acc.z, lane + 30);
        q.w = acc.w + __shfl(acc.w, lane + 30);
        T.x = q.x + __shfl(q.x, lane + 10) + __shfl(q.x, lane + 20);
        T.y = q.y + __shfl(q.y, lane + 10) + __shfl(q.y, lane + 20);
        T.z = q.z + __shfl(q.z, lane + 10) + __shfl(q.z, lane + 20);
        T.w = q.w + __shfl(q.w, lane + 10) + __shfl(q.w, lane + 20);
        if (lane < W)
            ff[(unsigned)(row0 + rloc) * ROW_F4 + sb + lane] = T;
    }
}

// ---------------------------------------------------------------------------
// Phase 2: FM reduction over materialized field_f + first order.
__global__ __launch_bounds__(256) void ffm_final(
    const float*  __restrict__ dense,
    const int*    __restrict__ sparse,
    const float*  __restrict__ w0,
    const float*  __restrict__ w,
    const float4* __restrict__ ff,
    float*        __restrict__ out)
{
    const int wave = threadIdx.x >> 6;
    const int lane = threadIdx.x & 63;
    const int b = blockIdx.x * 4 + wave;

    float4 s = make_float4(0.f, 0.f, 0.f, 0.f);
    float  sq = 0.f;
#pragma unroll
    for (int p = 0; p < 3; ++p) {
        const int e4 = lane + 64 * p;
        if (e4 < ROW_F4) {
            const float4 acc = ff[(unsigned)b * ROW_F4 + e4];
            s.x += acc.x; s.y += acc.y; s.z += acc.z; s.w += acc.w;
            sq  += acc.x*acc.x + acc.y*acc.y + acc.z*acc.z + acc.w*acc.w;
        }
    }
#pragma unroll
    for (int m = 4; m <= 32; m <<= 1) {
        s.x += __shfl_xor(s.x, m); s.y += __shfl_xor(s.y, m);
        s.z += __shfl_xor(s.z, m); s.w += __shfl_xor(s.w, m);
    }
    float s2 = s.x*s.x + s.y*s.y + s.z*s.z + s.w*s.w;
    s2 += __shfl_xor(s2, 1);
    s2 += __shfl_xor(s2, 2);
#pragma unroll
    for (int m = 1; m <= 32; m <<= 1) sq += __shfl_xor(sq, m);

    float fo = 0.f;
    if (lane < NSPARSE) fo = w[sparse[b * NSPARSE + lane] + NDENSE + 1000 * lane];
    if (lane < NDENSE)  fo += dense[b * NDENSE + lane] * w[lane];
#pragma unroll
    for (int m = 1; m <= 32; m <<= 1) fo += __shfl_xor(fo, m);

    if (lane == 0) out[b] = w0[0] + fo + 0.5f * (s2 - sq);
}

// ---------------------------------------------------------------------------
// Fallback: R1 fused kernel (only if ws too small for field_f buffer).
__global__ __launch_bounds__(256) void ffm_fused(
    const float* __restrict__ dense, const int* __restrict__ sparse,
    const float* __restrict__ w0, const float* __restrict__ w,
    const float4* __restrict__ v4, float* __restrict__ out)
{
    const int wave = threadIdx.x >> 6;
    const int lane = threadIdx.x & 63;
    const int b = blockIdx.x * 4 + wave;

    float dv[NDENSE];
#pragma unroll
    for (int d = 0; d < NDENSE; ++d) dv[d] = dense[b * NDENSE + d];
    int myidx = 0;
    if (lane < NSPARSE) myidx = sparse[b * NSPARSE + lane] + NDENSE + 1000 * lane;

    float4 s = make_float4(0.f, 0.f, 0.f, 0.f);
    float  sq = 0.f;
#pragma unroll
    for (int p = 0; p < 3; ++p) {
        const int e4 = lane + 64 * p;
        if (e4 < ROW_F4) {
            float4 acc = make_float4(0.f, 0.f, 0.f, 0.f);
#pragma unroll
            for (int d = 0; d < NDENSE; ++d) {
                const float4 vv = v4[d * ROW_F4 + e4];
                acc.x += dv[d]*vv.x; acc.y += dv[d]*vv.y;
                acc.z += dv[d]*vv.z; acc.w += dv[d]*vv.w;
            }
#pragma unroll
            for (int j = 0; j < NSPARSE; ++j) {
                const int ij = __shfl(myidx, j);
                const float4 vv = v4[(size_t)ij * ROW_F4 + e4];
                acc.x += vv.x; acc.y += vv.y; acc.z += vv.z; acc.w += vv.w;
            }
            s.x += acc.x; s.y += acc.y; s.z += acc.z; s.w += acc.w;
            sq  += acc.x*acc.x + acc.y*acc.y + acc.z*acc.z + acc.w*acc.w;
        }
    }
#pragma unroll
    for (int m = 4; m <= 32; m <<= 1) {
        s.x += __shfl_xor(s.x, m); s.y += __shfl_xor(s.y, m);
        s.z += __shfl_xor(s.z, m); s.w += __shfl_xor(s.w, m);
    }
    float s2 = s.x*s.x + s.y*s.y + s.z*s.z + s.w*s.w;
    s2 += __shfl_xor(s2, 1);
    s2 += __shfl_xor(s2, 2);
#pragma unroll
    for (int m = 1; m <= 32; m <<= 1) sq += __shfl_xor(sq, m);
    float fo = 0.f;
    if (lane < NSPARSE) fo = w[myidx];
    if (lane < NDENSE)  fo += dense[b * NDENSE + lane] * w[lane];
#pragma unroll
    for (int m = 1; m <= 32; m <<= 1) fo += __shfl_xor(fo, m);
    if (lane == 0) out[b] = w0[0] + fo + 0.5f * (s2 - sq);
}

extern "C" void kernel_launch(void* const* d_in, const int* in_sizes, int n_in,
                              void* d_out, int out_size, void* d_ws, size_t ws_size,
                              hipStream_t stream) {
    const float*  dense  = (const float*)d_in[0];
    const int*    sparse = (const int*)d_in[1];
    const float*  w0     = (const float*)d_in[2];
    const float*  w      = (const float*)d_in[3];
    const float4* v4     = (const float4*)d_in[4];
    float* out = (float*)d_out;

    const size_t ff_bytes = (size_t)BATCH * ROW_F4 * sizeof(float4); // 10.2 MB

    if (ws_size >= ff_bytes) {
        float4* ffp = (float4*)d_ws;
        // 16 slices x 256 chunks = 4096 blocks; blockIdx%8 pins slice pair to XCD
        hipLaunchKernelGGL(ffm_slice, dim3(16 * CHUNKS), dim3(256), 0, stream,
                           dense, sparse, v4, ffp);
        hipLaunchKernelGGL(ffm_final, dim3(BATCH / 4), dim3(256), 0, stream,
                           dense, sparse, w0, w, ffp, out);
    } else {
        hipLaunchKernelGGL(ffm_fused, dim3(BATCH / 4), dim3(256), 0, stream,
                           dense, sparse, w0, w, v4, out);
    }
}

// Round 4
// 40.869 us; speedup vs baseline: 1.4286x; 1.1911x over previous
//
#include <hip/hip_runtime.h>

#define NDENSE 13
#define NSPARSE 26
#define NSRC 39      // 26 sparse gathers + 13 dense-weighted rows
#define ROW_F4 156   // 39*16/4 float4 per v row
#define BATCH 4096
#define RPB 64       // rows per block in phase 1
#define CHUNKS (BATCH / RPB)   // 64
#define SL_PER_XCD 5 // 40 padded slices / 8 XCDs

// ---------------------------------------------------------------------------
// Phase 1: field-aligned sliced gather, XCD-pinned, register-resident MLP.
// Slice = one field f (64 B per v-row). Slice working set = 26013*64B = 1.66MB
// -> L2-resident on its XCD. blockIdx = xcd + 8*(slice_local*CHUNKS + chunk),
// so consecutive blocks round-robin XCDs and each XCD sees its 5 slices in
// sequence. Lane owns (row, k-quarter): 39-deep unconditional unrolled
// gather-FMA, all loads independent -> full MLP.
__global__ __launch_bounds__(256) void ffm_slice2(
    const float*  __restrict__ dense,    // [B,13]
    const int*    __restrict__ sparse,   // [B,26]
    const float4* __restrict__ v4,       // [26013*156]
    float4*       __restrict__ ff)       // [B*156] field_f output
{
    const int xcd   = blockIdx.x & 7;
    const int rest  = blockIdx.x >> 3;
    const int slice = xcd * SL_PER_XCD + (rest >> 6);   // field index
    const int chunk = rest & (CHUNKS - 1);
    if (slice >= NSRC) return;                          // padded slices idle

    __shared__ int   vrow_s[RPB][NSRC];
    __shared__ float wgt_s [RPB][NSRC];

    const int t = threadIdx.x;
    const int row0 = chunk * RPB;
    for (int i = t; i < RPB * NSPARSE; i += 256) {
        const int r = i / NSPARSE, j = i % NSPARSE;
        vrow_s[r][j] = sparse[(row0 + r) * NSPARSE + j] + NDENSE + 1000 * j;
        wgt_s [r][j] = 1.0f;
    }
    for (int i = t; i < RPB * NDENSE; i += 256) {
        const int r = i / NDENSE, d = i % NDENSE;
        vrow_s[r][NSPARSE + d] = d;
        wgt_s [r][NSPARSE + d] = dense[(row0 + r) * NDENSE + d];
    }
    __syncthreads();

    const int lane = t & 63;
    const int wv   = t >> 6;
    const int rl   = (wv << 4) + (lane >> 2);   // 0..63 local row
    const int c    = lane & 3;                  // k-quarter within field
    const int fb   = slice * 4 + c;             // f4 column within v row

    float4 acc = make_float4(0.f, 0.f, 0.f, 0.f);
#pragma unroll
    for (int src = 0; src < NSRC; ++src) {
        const int   vr = vrow_s[rl][src];
        const float wg = wgt_s [rl][src];
        const float4 g = v4[(unsigned)vr * ROW_F4 + fb];
        acc.x += wg * g.x; acc.y += wg * g.y;
        acc.z += wg * g.z; acc.w += wg * g.w;
    }
    ff[(unsigned)(row0 + rl) * ROW_F4 + fb] = acc;
}

// ---------------------------------------------------------------------------
// Phase 2: FM reduction over materialized field_f + first order. (R3-proven)
__global__ __launch_bounds__(256) void ffm_final(
    const float*  __restrict__ dense,
    const int*    __restrict__ sparse,
    const float*  __restrict__ w0,
    const float*  __restrict__ w,
    const float4* __restrict__ ff,
    float*        __restrict__ out)
{
    const int wave = threadIdx.x >> 6;
    const int lane = threadIdx.x & 63;
    const int b = blockIdx.x * 4 + wave;

    float4 s = make_float4(0.f, 0.f, 0.f, 0.f);
    float  sq = 0.f;
#pragma unroll
    for (int p = 0; p < 3; ++p) {
        const int e4 = lane + 64 * p;
        if (e4 < ROW_F4) {
            const float4 acc = ff[(unsigned)b * ROW_F4 + e4];
            s.x += acc.x; s.y += acc.y; s.z += acc.z; s.w += acc.w;
            sq  += acc.x*acc.x + acc.y*acc.y + acc.z*acc.z + acc.w*acc.w;
        }
    }
#pragma unroll
    for (int m = 4; m <= 32; m <<= 1) {
        s.x += __shfl_xor(s.x, m); s.y += __shfl_xor(s.y, m);
        s.z += __shfl_xor(s.z, m); s.w += __shfl_xor(s.w, m);
    }
    float s2 = s.x*s.x + s.y*s.y + s.z*s.z + s.w*s.w;
    s2 += __shfl_xor(s2, 1);
    s2 += __shfl_xor(s2, 2);
#pragma unroll
    for (int m = 1; m <= 32; m <<= 1) sq += __shfl_xor(sq, m);

    float fo = 0.f;
    if (lane < NSPARSE) fo = w[sparse[b * NSPARSE + lane] + NDENSE + 1000 * lane];
    if (lane < NDENSE)  fo += dense[b * NDENSE + lane] * w[lane];
#pragma unroll
    for (int m = 1; m <= 32; m <<= 1) fo += __shfl_xor(fo, m);

    if (lane == 0) out[b] = w0[0] + fo + 0.5f * (s2 - sq);
}

// ---------------------------------------------------------------------------
// Fallback: R1 fused kernel (only if ws too small for field_f buffer).
__global__ __launch_bounds__(256) void ffm_fused(
    const float* __restrict__ dense, const int* __restrict__ sparse,
    const float* __restrict__ w0, const float* __restrict__ w,
    const float4* __restrict__ v4, float* __restrict__ out)
{
    const int wave = threadIdx.x >> 6;
    const int lane = threadIdx.x & 63;
    const int b = blockIdx.x * 4 + wave;

    float dv[NDENSE];
#pragma unroll
    for (int d = 0; d < NDENSE; ++d) dv[d] = dense[b * NDENSE + d];
    int myidx = 0;
    if (lane < NSPARSE) myidx = sparse[b * NSPARSE + lane] + NDENSE + 1000 * lane;

    float4 s = make_float4(0.f, 0.f, 0.f, 0.f);
    float  sq = 0.f;
#pragma unroll
    for (int p = 0; p < 3; ++p) {
        const int e4 = lane + 64 * p;
        if (e4 < ROW_F4) {
            float4 acc = make_float4(0.f, 0.f, 0.f, 0.f);
#pragma unroll
            for (int d = 0; d < NDENSE; ++d) {
                const float4 vv = v4[d * ROW_F4 + e4];
                acc.x += dv[d]*vv.x; acc.y += dv[d]*vv.y;
                acc.z += dv[d]*vv.z; acc.w += dv[d]*vv.w;
            }
#pragma unroll
            for (int j = 0; j < NSPARSE; ++j) {
                const int ij = __shfl(myidx, j);
                const float4 vv = v4[(size_t)ij * ROW_F4 + e4];
                acc.x += vv.x; acc.y += vv.y; acc.z += vv.z; acc.w += vv.w;
            }
            s.x += acc.x; s.y += acc.y; s.z += acc.z; s.w += acc.w;
            sq  += acc.x*acc.x + acc.y*acc.y + acc.z*acc.z + acc.w*acc.w;
        }
    }
#pragma unroll
    for (int m = 4; m <= 32; m <<= 1) {
        s.x += __shfl_xor(s.x, m); s.y += __shfl_xor(s.y, m);
        s.z += __shfl_xor(s.z, m); s.w += __shfl_xor(s.w, m);
    }
    float s2 = s.x*s.x + s.y*s.y + s.z*s.z + s.w*s.w;
    s2 += __shfl_xor(s2, 1);
    s2 += __shfl_xor(s2, 2);
#pragma unroll
    for (int m = 1; m <= 32; m <<= 1) sq += __shfl_xor(sq, m);
    float fo = 0.f;
    if (lane < NSPARSE) fo = w[myidx];
    if (lane < NDENSE)  fo += dense[b * NDENSE + lane] * w[lane];
#pragma unroll
    for (int m = 1; m <= 32; m <<= 1) fo += __shfl_xor(fo, m);
    if (lane == 0) out[b] = w0[0] + fo + 0.5f * (s2 - sq);
}

extern "C" void kernel_launch(void* const* d_in, const int* in_sizes, int n_in,
                              void* d_out, int out_size, void* d_ws, size_t ws_size,
                              hipStream_t stream) {
    const float*  dense  = (const float*)d_in[0];
    const int*    sparse = (const int*)d_in[1];
    const float*  w0     = (const float*)d_in[2];
    const float*  w      = (const float*)d_in[3];
    const float4* v4     = (const float4*)d_in[4];
    float* out = (float*)d_out;

    const size_t ff_bytes = (size_t)BATCH * ROW_F4 * sizeof(float4); // 10.2 MB

    if (ws_size >= ff_bytes) {
        float4* ffp = (float4*)d_ws;
        // 8 XCDs x 5 slices x 64 chunks = 2560 blocks (slice>=39 exit early)
        hipLaunchKernelGGL(ffm_slice2, dim3(8 * SL_PER_XCD * CHUNKS), dim3(256), 0, stream,
                           dense, sparse, v4, ffp);
        hipLaunchKernelGGL(ffm_final, dim3(BATCH / 4), dim3(256), 0, stream,
                           dense, sparse, w0, w, ffp, out);
    } else {
        hipLaunchKernelGGL(ffm_fused, dim3(BATCH / 4), dim3(256), 0, stream,
                           dense, sparse, w0, w, v4, out);
    }
}

// Round 5
// 39.804 us; speedup vs baseline: 1.4668x; 1.0268x over previous
//
#include <hip/hip_runtime.h>

#define NDENSE 13
#define NSPARSE 26
#define ROW_F4 156   // 39*16/4 float4 per v row
#define BATCH 4096
#define RPB 64       // rows per block in phase 1
#define CHUNKS (BATCH / RPB)   // 64
#define SL_PER_XCD 5 // 40 padded slices / 8 XCDs

// ---------------------------------------------------------------------------
// Phase 1: field-aligned sliced gather, XCD-pinned, explicit-MLP.
// Slice = one field f (64 B per v-row). Slice WS = 26013*64B = 1.66MB -> L2-
// resident on its XCD (blockIdx%8 ~ XCD round-robin). Dense contribution comes
// from an LDS-staged v[:13] slice (832 B) instead of 13 global gathers.
// Each lane owns (row, k-quarter); 26 gathers issued into g[26] before any
// accumulation -> max memory-level parallelism.
__global__ __launch_bounds__(256) void ffm_slice3(
    const float*  __restrict__ dense,    // [B,13]
    const int*    __restrict__ sparse,   // [B,26]
    const float4* __restrict__ v4,       // [26013*156]
    float4*       __restrict__ ff)       // [B*156] field_f output
{
    const int xcd   = blockIdx.x & 7;
    const int rest  = blockIdx.x >> 3;
    const int slice = xcd * SL_PER_XCD + (rest >> 6);   // field index
    const int chunk = rest & (CHUNKS - 1);

    __shared__ int    vrow_s[RPB * NSPARSE];  // 6656 B
    __shared__ float  dsh   [RPB * NDENSE];   // 3328 B
    __shared__ float4 vsh   [NDENSE * 4];     //  832 B: v[:13] slice columns

    if (slice >= 39) return;                  // 64 padded blocks idle

    const int t = threadIdx.x;
    const int row0 = chunk * RPB;
    for (int i = t; i < RPB * NSPARSE; i += 256) {
        const int r = i / NSPARSE, j = i % NSPARSE;
        vrow_s[i] = sparse[(row0 + r) * NSPARSE + j] + NDENSE + 1000 * j;
    }
    for (int i = t; i < RPB * NDENSE; i += 256)
        dsh[i] = dense[row0 * NDENSE + i];
    if (t < NDENSE * 4)
        vsh[t] = v4[(t >> 2) * ROW_F4 + slice * 4 + (t & 3)];
    __syncthreads();

    const int lane = t & 63;
    const int wv   = t >> 6;
    const int rl   = (wv << 4) + (lane >> 2);   // 0..63 local row
    const int c    = lane & 3;                  // k-quarter within field
    const int fb   = slice * 4 + c;             // f4 column within v row

    // Dense part: 13 LDS-FMAs (no global traffic)
    float4 acc = make_float4(0.f, 0.f, 0.f, 0.f);
#pragma unroll
    for (int d = 0; d < NDENSE; ++d) {
        const float  wg = dsh[rl * NDENSE + d];
        const float4 vv = vsh[d * 4 + c];
        acc.x += wg * vv.x; acc.y += wg * vv.y;
        acc.z += wg * vv.z; acc.w += wg * vv.w;
    }

    // 26 independent gathers, all issued before accumulation
    float4 g[NSPARSE];
#pragma unroll
    for (int j = 0; j < NSPARSE; ++j)
        g[j] = v4[(unsigned)vrow_s[rl * NSPARSE + j] * ROW_F4 + fb];
#pragma unroll
    for (int j = 0; j < NSPARSE; ++j) {
        acc.x += g[j].x; acc.y += g[j].y; acc.z += g[j].z; acc.w += g[j].w;
    }

    ff[(unsigned)(row0 + rl) * ROW_F4 + fb] = acc;
}

// ---------------------------------------------------------------------------
// Phase 2: FM reduction over materialized field_f + first order. (R3-proven)
__global__ __launch_bounds__(256) void ffm_final(
    const float*  __restrict__ dense,
    const int*    __restrict__ sparse,
    const float*  __restrict__ w0,
    const float*  __restrict__ w,
    const float4* __restrict__ ff,
    float*        __restrict__ out)
{
    const int wave = threadIdx.x >> 6;
    const int lane = threadIdx.x & 63;
    const int b = blockIdx.x * 4 + wave;

    float4 s = make_float4(0.f, 0.f, 0.f, 0.f);
    float  sq = 0.f;
#pragma unroll
    for (int p = 0; p < 3; ++p) {
        const int e4 = lane + 64 * p;
        if (e4 < ROW_F4) {
            const float4 acc = ff[(unsigned)b * ROW_F4 + e4];
            s.x += acc.x; s.y += acc.y; s.z += acc.z; s.w += acc.w;
            sq  += acc.x*acc.x + acc.y*acc.y + acc.z*acc.z + acc.w*acc.w;
        }
    }
#pragma unroll
    for (int m = 4; m <= 32; m <<= 1) {
        s.x += __shfl_xor(s.x, m); s.y += __shfl_xor(s.y, m);
        s.z += __shfl_xor(s.z, m); s.w += __shfl_xor(s.w, m);
    }
    float s2 = s.x*s.x + s.y*s.y + s.z*s.z + s.w*s.w;
    s2 += __shfl_xor(s2, 1);
    s2 += __shfl_xor(s2, 2);
#pragma unroll
    for (int m = 1; m <= 32; m <<= 1) sq += __shfl_xor(sq, m);

    float fo = 0.f;
    if (lane < NSPARSE) fo = w[sparse[b * NSPARSE + lane] + NDENSE + 1000 * lane];
    if (lane < NDENSE)  fo += dense[b * NDENSE + lane] * w[lane];
#pragma unroll
    for (int m = 1; m <= 32; m <<= 1) fo += __shfl_xor(fo, m);

    if (lane == 0) out[b] = w0[0] + fo + 0.5f * (s2 - sq);
}

// ---------------------------------------------------------------------------
// Fallback: R1 fused kernel (only if ws too small for field_f buffer).
__global__ __launch_bounds__(256) void ffm_fused(
    const float* __restrict__ dense, const int* __restrict__ sparse,
    const float* __restrict__ w0, const float* __restrict__ w,
    const float4* __restrict__ v4, float* __restrict__ out)
{
    const int wave = threadIdx.x >> 6;
    const int lane = threadIdx.x & 63;
    const int b = blockIdx.x * 4 + wave;

    float dv[NDENSE];
#pragma unroll
    for (int d = 0; d < NDENSE; ++d) dv[d] = dense[b * NDENSE + d];
    int myidx = 0;
    if (lane < NSPARSE) myidx = sparse[b * NSPARSE + lane] + NDENSE + 1000 * lane;

    float4 s = make_float4(0.f, 0.f, 0.f, 0.f);
    float  sq = 0.f;
#pragma unroll
    for (int p = 0; p < 3; ++p) {
        const int e4 = lane + 64 * p;
        if (e4 < ROW_F4) {
            float4 acc = make_float4(0.f, 0.f, 0.f, 0.f);
#pragma unroll
            for (int d = 0; d < NDENSE; ++d) {
                const float4 vv = v4[d * ROW_F4 + e4];
                acc.x += dv[d]*vv.x; acc.y += dv[d]*vv.y;
                acc.z += dv[d]*vv.z; acc.w += dv[d]*vv.w;
            }
#pragma unroll
            for (int j = 0; j < NSPARSE; ++j) {
                const int ij = __shfl(myidx, j);
                const float4 vv = v4[(size_t)ij * ROW_F4 + e4];
                acc.x += vv.x; acc.y += vv.y; acc.z += vv.z; acc.w += vv.w;
            }
            s.x += acc.x; s.y += acc.y; s.z += acc.z; s.w += acc.w;
            sq  += acc.x*acc.x + acc.y*acc.y + acc.z*acc.z + acc.w*acc.w;
        }
    }
#pragma unroll
    for (int m = 4; m <= 32; m <<= 1) {
        s.x += __shfl_xor(s.x, m); s.y += __shfl_xor(s.y, m);
        s.z += __shfl_xor(s.z, m); s.w += __shfl_xor(s.w, m);
    }
    float s2 = s.x*s.x + s.y*s.y + s.z*s.z + s.w*s.w;
    s2 += __shfl_xor(s2, 1);
    s2 += __shfl_xor(s2, 2);
#pragma unroll
    for (int m = 1; m <= 32; m <<= 1) sq += __shfl_xor(sq, m);
    float fo = 0.f;
    if (lane < NSPARSE) fo = w[myidx];
    if (lane < NDENSE)  fo += dense[b * NDENSE + lane] * w[lane];
#pragma unroll
    for (int m = 1; m <= 32; m <<= 1) fo += __shfl_xor(fo, m);
    if (lane == 0) out[b] = w0[0] + fo + 0.5f * (s2 - sq);
}

extern "C" void kernel_launch(void* const* d_in, const int* in_sizes, int n_in,
                              void* d_out, int out_size, void* d_ws, size_t ws_size,
                              hipStream_t stream) {
    const float*  dense  = (const float*)d_in[0];
    const int*    sparse = (const int*)d_in[1];
    const float*  w0     = (const float*)d_in[2];
    const float*  w      = (const float*)d_in[3];
    const float4* v4     = (const float4*)d_in[4];
    float* out = (float*)d_out;

    const size_t ff_bytes = (size_t)BATCH * ROW_F4 * sizeof(float4); // 10.2 MB

    if (ws_size >= ff_bytes) {
        float4* ffp = (float4*)d_ws;
        // 8 XCDs x 5 slices x 64 chunks = 2560 blocks (slice>=39 exit early)
        hipLaunchKernelGGL(ffm_slice3, dim3(8 * SL_PER_XCD * CHUNKS), dim3(256), 0, stream,
                           dense, sparse, v4, ffp);
        hipLaunchKernelGGL(ffm_final, dim3(BATCH / 4), dim3(256), 0, stream,
                           dense, sparse, w0, w, ffp, out);
    } else {
        hipLaunchKernelGGL(ffm_fused, dim3(BATCH / 4), dim3(256), 0, stream,
                           dense, sparse, w0, w, v4, out);
    }
}